// Round 2
// baseline (786.409 us; speedup 1.0000x reference)
//
#include <hip/hip_runtime.h>

// ---------------------------------------------------------------------------
// CausalLinearAttentionRSEEncoder: full block implementation
// B=4 T=2048 D=1024 H=16 K=64 BK=32 FFN=4096 LORA=48 CHUNK=64 NC=32
// ---------------------------------------------------------------------------

typedef __bf16 bf16x8 __attribute__((ext_vector_type(8)));
typedef float f32x4 __attribute__((ext_vector_type(4)));

__device__ __forceinline__ unsigned short f2bf(float f) {
  unsigned int u = __builtin_bit_cast(unsigned int, f);
  u += 0x7FFFu + ((u >> 16) & 1u);
  return (unsigned short)(u >> 16);
}

__device__ __forceinline__ void gload_lds16(const void* g, void* l) {
  __builtin_amdgcn_global_load_lds((const __attribute__((address_space(1))) void*)g,
                                   (__attribute__((address_space(3))) void*)l, 16, 0, 0);
}

__device__ __forceinline__ float gelu_tanh(float v) {
  float c = fmaf(0.044715f * v * v, v, v);
  return 0.5f * v * (1.f + tanhf(0.7978845608028654f * c));
}

// -------------------------------- fill (ws guard) ---------------------------
__global__ void fill_kernel(float* p, float v, int n) {
  int i = blockIdx.x * 256 + threadIdx.x;
  if (i < n) p[i] = v;
}

// -------------------------------- LayerNorm -> bf16 -------------------------
__global__ __launch_bounds__(256) void ln_kernel(
    const float* __restrict__ x, const float* __restrict__ g,
    const float* __restrict__ b, unsigned short* __restrict__ out) {
  const int row = blockIdx.x, tid = threadIdx.x;
  float4 v = ((const float4*)(x + (size_t)row * 1024))[tid];
  float s = v.x + v.y + v.z + v.w;
  float sq = v.x * v.x + v.y * v.y + v.z * v.z + v.w * v.w;
#pragma unroll
  for (int o = 32; o > 0; o >>= 1) { s += __shfl_xor(s, o); sq += __shfl_xor(sq, o); }
  __shared__ float red[8];
  const int wid = tid >> 6;
  if ((tid & 63) == 0) { red[wid] = s; red[4 + wid] = sq; }
  __syncthreads();
  s = red[0] + red[1] + red[2] + red[3];
  sq = red[4] + red[5] + red[6] + red[7];
  const float mean = s * (1.f / 1024.f);
  const float var = sq * (1.f / 1024.f) - mean * mean;
  const float rstd = rsqrtf(var + 1e-6f);
  float4 gv = ((const float4*)g)[tid];
  float4 bvv = ((const float4*)b)[tid];
  ushort4 o4;
  o4.x = f2bf((v.x - mean) * rstd * gv.x + bvv.x);
  o4.y = f2bf((v.y - mean) * rstd * gv.y + bvv.y);
  o4.z = f2bf((v.z - mean) * rstd * gv.z + bvv.z);
  o4.w = f2bf((v.w - mean) * rstd * gv.w + bvv.w);
  *(ushort4*)(out + (size_t)row * 1024 + tid * 4) = o4;
}

// ------------------------- weight transposes to bf16 ------------------------
__global__ __launch_bounds__(256) void transpose_bf16(
    const float* __restrict__ src, unsigned short* __restrict__ dst, int K, int N) {
  __shared__ float tile[32][33];
  const int n0 = blockIdx.x * 32, k0 = blockIdx.y * 32;
  const int tx = threadIdx.x, ty = threadIdx.y;
#pragma unroll
  for (int j = 0; j < 32; j += 8) tile[tx][ty + j] = src[(size_t)(k0 + ty + j) * N + n0 + tx];
  __syncthreads();
#pragma unroll
  for (int j = 0; j < 32; j += 8)
    dst[(size_t)(n0 + ty + j) * K + k0 + tx] = f2bf(tile[ty + j][tx]);
}

// WcatT[3200][1024]
__global__ __launch_bounds__(256) void prep_wcat(
    const float* __restrict__ Wq, const float* __restrict__ Wk,
    const float* __restrict__ Wv, const float* __restrict__ tw1,
    unsigned short* __restrict__ dst) {
  __shared__ float tile[32][33];
  const int r0 = blockIdx.x * 32, c0 = blockIdx.y * 32;
  const int tx = threadIdx.x, ty = threadIdx.y;
  const int r = r0 + tx;
#pragma unroll
  for (int j = 0; j < 32; j += 8) {
    const int c = c0 + ty + j;
    float v;
    if (r < 1024) v = Wq[(size_t)c * 1024 + r];
    else if (r < 2048) v = Wk[(size_t)c * 1024 + (r - 1024)];
    else if (r < 3072) v = Wv[(size_t)c * 1024 + (r - 2048)];
    else if (r < 3120) v = tw1[(size_t)c * 48 + (r - 3072)];
    else v = 0.f;
    tile[tx][ty + j] = v;
  }
  __syncthreads();
#pragma unroll
  for (int j = 0; j < 32; j += 8)
    dst[(size_t)(r0 + ty + j) * 1024 + c0 + tx] = f2bf(tile[ty + j][tx]);
}

__global__ void biascat_kernel(const float* bq, const float* bk, const float* bv, float* dst) {
  int i = blockIdx.x * 256 + threadIdx.x;
  if (i >= 3200) return;
  float v = 0.f;
  if (i < 1024) v = bq[i];
  else if (i < 2048) v = bk[i - 1024];
  else if (i < 3072) v = bv[i - 2048];
  dst[i] = v;
}

// ------------------------------- bf16 MFMA GEMM -----------------------------
template <int MODE>
__global__ __launch_bounds__(256) void gemm_kernel(
    const unsigned short* __restrict__ A, const unsigned short* __restrict__ BT,
    const float* __restrict__ bias, const float* __restrict__ res,
    void* __restrict__ out, int N, int Kd) {
  __shared__ unsigned short As[128 * 64];
  __shared__ unsigned short Bs[128 * 64];
  const int n0 = blockIdx.x * 128, m0 = blockIdx.y * 128;
  const int tid = threadIdx.x, wv = tid >> 6, ln = tid & 63;
  const int wm = wv >> 1, wn = wv & 1;
  const int l15 = ln & 15, lk = (ln >> 4) * 8;
  const int rsub = ln >> 3;
  const int csub = (ln & 7) * 8;
  f32x4 acc[4][4] = {};
  for (int k0 = 0; k0 < Kd; k0 += 64) {
#pragma unroll
    for (int jj = 0; jj < 4; ++jj) {
      const int r0 = (wv * 4 + jj) * 8;
      gload_lds16(A + (size_t)(m0 + r0 + rsub) * Kd + k0 + csub,
                  (char*)As + (wv * 4 + jj) * 1024);
      gload_lds16(BT + (size_t)(n0 + r0 + rsub) * Kd + k0 + csub,
                  (char*)Bs + (wv * 4 + jj) * 1024);
    }
    __syncthreads();
#pragma unroll
    for (int kk = 0; kk < 64; kk += 32) {
      bf16x8 av[4], bv[4];
#pragma unroll
      for (int f = 0; f < 4; ++f) {
        av[f] = *(const bf16x8*)&As[(wm * 64 + f * 16 + l15) * 64 + kk + lk];
        bv[f] = *(const bf16x8*)&Bs[(wn * 64 + f * 16 + l15) * 64 + kk + lk];
      }
#pragma unroll
      for (int fm = 0; fm < 4; ++fm)
#pragma unroll
        for (int fn = 0; fn < 4; ++fn)
          acc[fm][fn] = __builtin_amdgcn_mfma_f32_16x16x32_bf16(av[fm], bv[fn], acc[fm][fn], 0, 0, 0);
    }
    __syncthreads();
  }
  const int rb = (ln >> 4) * 4;
#pragma unroll
  for (int fm = 0; fm < 4; ++fm) {
#pragma unroll
    for (int fn = 0; fn < 4; ++fn) {
      const int row = m0 + wm * 64 + fm * 16 + rb;
      const int col = n0 + wn * 64 + fn * 16 + l15;
      const float bval = bias[col];
#pragma unroll
      for (int r = 0; r < 4; ++r) {
        float v = acc[fm][fn][r] + bval;
        const size_t oi = (size_t)(row + r) * N + col;
        if constexpr (MODE == 1) v += res[oi];
        if constexpr (MODE == 2) {
          ((unsigned short*)out)[oi] = f2bf(gelu_tanh(v));
        } else {
          ((float*)out)[oi] = v;
        }
      }
    }
  }
}

// -------------------------- LoRA2 + theta (clip) ----------------------------
__global__ __launch_bounds__(256) void lora2_kernel(
    const float* __restrict__ qkv, const float* __restrict__ w2,
    const float* __restrict__ tbase, float* __restrict__ theta) {
  __shared__ float lt[8][48];
  const int m0 = blockIdx.x * 32;
  const int tid = threadIdx.x;
  const int col = tid * 2;
  const float tb0 = tbase[col], tb1 = tbase[col + 1];
  for (int grp = 0; grp < 4; ++grp) {
    const int mg = m0 + grp * 8;
    __syncthreads();
    for (int idx = tid; idx < 384; idx += 256) {
      const int tok = idx / 48, jj = idx % 48;
      lt[tok][jj] = tanhf(qkv[(size_t)(mg + tok) * 3200 + 3072 + jj]);
    }
    __syncthreads();
    float a0[8], a1[8];
#pragma unroll
    for (int tok = 0; tok < 8; ++tok) { a0[tok] = tb0; a1[tok] = tb1; }
    for (int jj = 0; jj < 48; ++jj) {
      const float2 w = *(const float2*)&w2[(size_t)jj * 512 + col];
#pragma unroll
      for (int tok = 0; tok < 8; ++tok) {
        const float l = lt[tok][jj];
        a0[tok] = fmaf(l, w.x, a0[tok]);
        a1[tok] = fmaf(l, w.y, a1[tok]);
      }
    }
    const float CL = 1.5707963267948966f;
#pragma unroll
    for (int tok = 0; tok < 8; ++tok) {
      float c0 = fminf(fmaxf(a0[tok], -CL), CL);
      float c1 = fminf(fmaxf(a1[tok], -CL), CL);
      *(float2*)&theta[(size_t)(mg + tok) * 512 + col] = make_float2(c0, c1);
    }
  }
}

// ------------------------------- pass A (v2: 4 waves) -----------------------
// Block = one (b,h,chunk), 256 threads.
// Phase 1: params for all (t,bk) in parallel -> LDS.
// Phase 2: segmented prefix scan of (lam, th).
// Phase 3: Qg (layout [cid][t][bk][2]) + Dg in parallel.
// Phase 4: recurrence, wave w owns bk in [8w,8w+8); y merged via LDS atomics.
__global__ __launch_bounds__(256) void passA_kernel(
    const float* __restrict__ qkv, const float* __restrict__ theta,
    const float* __restrict__ lamb, const float* __restrict__ eta,
    float* __restrict__ yi, float* __restrict__ Qg,
    float* __restrict__ Tg, float* __restrict__ Dg) {
  const int c = blockIdx.x, bh = blockIdx.y;
  const int b = bh >> 4, h = bh & 15;
  const int cid = bh * 32 + c;
  const int tid = threadIdx.x;
  const int bk = tid & 31, trow = tid >> 5;  // trow 0..7, owns t = trow*8 .. trow*8+7
  const int m0 = b * 2048 + c * 64;

  __shared__ float Pzk[64][32][4];   // {zr, zi, kr, ki}  32 KB
  __shared__ float Pq[64][32][2];    // {qr, qi}          16 KB
  __shared__ float LTY[4096];        // lam[t*32+bk] | th[2048+t*32+bk]; later Y[t*64+v]
  __shared__ float Seg[2][8][32];    // per-segment sums of lam/th

  // ---- phase 1 ----
  const float lb = lamb[h * 32 + bk], et = eta[h * 32 + bk];
  float sL = 0.f, sT = 0.f;
#pragma unroll
  for (int i = 0; i < 8; ++i) {
    const int t = trow * 8 + i;
    const size_t m = (size_t)(m0 + t);
    const float th = theta[m * 512 + h * 32 + bk];
    const float lam = fmaf(et * th, th, lb);
    LTY[t * 32 + bk] = lam;
    LTY[2048 + t * 32 + bk] = th;
    sL += lam; sT += th;
    const float e = __expf(-lam);
    float sn, cs;
    __sincosf(th, &sn, &cs);
    const float2 kp = *(const float2*)&qkv[m * 3200 + 1024 + h * 64 + 2 * bk];
    const float2 qp = *(const float2*)&qkv[m * 3200 + h * 64 + 2 * bk];
    float4 z4;
    z4.x = e * cs; z4.y = e * sn;
    z4.z = kp.x > 0.f ? kp.x + 1.f : __expf(kp.x);
    z4.w = kp.y > 0.f ? kp.y + 1.f : __expf(kp.y);
    *(float4*)&Pzk[t][bk][0] = z4;
    *(float2*)&Pq[t][bk][0] = make_float2(qp.x, qp.y);
  }
  Seg[0][trow][bk] = sL; Seg[1][trow][bk] = sT;
  __syncthreads();

  // ---- phase 2: exclusive prefix of segment sums (redundant per thread) ----
  float offL = 0.f, offT = 0.f;
  for (int g = 0; g < trow; ++g) { offL += Seg[0][g][bk]; offT += Seg[1][g][bk]; }

  // ---- phase 3: Qg / Dg ----
  float cumL = offL, cumT = offT;
#pragma unroll
  for (int i = 0; i < 8; ++i) {
    const int t = trow * 8 + i;
    cumL += LTY[t * 32 + bk];
    cumT += LTY[2048 + t * 32 + bk];
    const float de = __expf(-cumL);
    float dsn, dcs;
    __sincosf(cumT, &dsn, &dcs);
    const float qr = Pq[t][bk][0], qi = Pq[t][bk][1];
    const float ar = de * (qr * dcs + qi * dsn);
    const float ai = de * (qr * dsn - qi * dcs);
    *(float2*)&Qg[((size_t)cid * 64 + t) * 64 + 2 * bk] = make_float2(ar, ai);
    if (t == 63) {
      Dg[((size_t)cid * 32 + bk) * 2 + 0] = de * dcs;
      Dg[((size_t)cid * 32 + bk) * 2 + 1] = de * dsn;
    }
  }
  __syncthreads();

  // ---- zero Y (aliases LTY) ----
  const float4 z4 = make_float4(0.f, 0.f, 0.f, 0.f);
  for (int i = tid * 4; i < 4096; i += 1024) *(float4*)&LTY[i] = z4;
  __syncthreads();

  // ---- phase 4: recurrence ----
  const int wv = tid >> 6, lane = tid & 63;
  const int bk0 = wv * 8;
  float Sr[8], Si[8];
#pragma unroll
  for (int i = 0; i < 8; ++i) { Sr[i] = 0.f; Si[i] = 0.f; }
  float vnext = qkv[(size_t)m0 * 3200 + 2048 + h * 64 + lane];
  for (int t = 0; t < 64; ++t) {
    const float vcur = vnext;
    if (t < 63) vnext = qkv[(size_t)(m0 + t + 1) * 3200 + 2048 + h * 64 + lane];
    float y = 0.f;
#pragma unroll
    for (int kk = 0; kk < 8; ++kk) {
      const float4 p = *(const float4*)&Pzk[t][bk0 + kk][0];   // LDS broadcast
      const float2 qq = *(const float2*)&Pq[t][bk0 + kk][0];   // LDS broadcast
      const float nr = fmaf(p.x, Sr[kk], fmaf(-p.y, Si[kk], p.z * vcur));
      const float ni = fmaf(p.x, Si[kk], fmaf(p.y, Sr[kk], p.w * vcur));
      Sr[kk] = nr; Si[kk] = ni;
      y = fmaf(qq.x, nr, fmaf(qq.y, ni, y));
    }
    atomicAdd(&LTY[t * 64 + lane], y);
  }
#pragma unroll
  for (int kk = 0; kk < 8; ++kk)
    *(float2*)&Tg[(((size_t)cid * 32 + bk0 + kk) * 64 + lane) * 2] = make_float2(Sr[kk], Si[kk]);
  __syncthreads();
  for (int i = tid * 4; i < 4096; i += 1024)
    *(float4*)&yi[(size_t)cid * 4096 + i] = *(const float4*)&LTY[i];
}

// ------------------------------- pass B (scan) ------------------------------
__global__ __launch_bounds__(256) void scanB_kernel(
    const float* __restrict__ Tg, const float* __restrict__ Dg, float* __restrict__ Cg) {
  const int bh = blockIdx.x;
  const int tid = threadIdx.x, wv = tid >> 6, lane = tid & 63;
  const int bkb = wv * 8;
  float Cr[8], Ci[8];
#pragma unroll
  for (int i = 0; i < 8; ++i) { Cr[i] = 0.f; Ci[i] = 0.f; }
  for (int c = 0; c < 32; ++c) {
    const size_t cid = (size_t)bh * 32 + c;
    float2 tv[8], dv[8];
#pragma unroll
    for (int i = 0; i < 8; ++i) {
      tv[i] = *(const float2*)&Tg[((cid * 32 + bkb + i) * 64 + lane) * 2];
      dv[i] = *(const float2*)&Dg[(cid * 32 + bkb + i) * 2];
    }
#pragma unroll
    for (int i = 0; i < 8; ++i) {
      *(float2*)&Cg[((cid * 32 + bkb + i) * 64 + lane) * 2] = make_float2(Cr[i], Ci[i]);
      const float nr = fmaf(dv[i].x, Cr[i], fmaf(-dv[i].y, Ci[i], tv[i].x));
      const float ni = fmaf(dv[i].x, Ci[i], fmaf(dv[i].y, Cr[i], tv[i].y));
      Cr[i] = nr; Ci[i] = ni;
    }
  }
}

// ------------------------------- pass C (v2: 4 waves) -----------------------
// y = y_intra + Re(qd . C_in); wave w handles t in [16w, 16w+16)
__global__ __launch_bounds__(256) void passC_kernel(
    const float* __restrict__ yi, const float* __restrict__ Qg,
    const float* __restrict__ Cg, unsigned short* __restrict__ attn) {
  const int c = blockIdx.x, bh = blockIdx.y;
  const int b = bh >> 4, h = bh & 15;
  const int cid = bh * 32 + c;
  const int tid = threadIdx.x;
  const int wv = tid >> 6, lane = tid & 63;
  __shared__ float Qs[4096];   // [t][bk][2], 16 KB
  for (int i = tid * 4; i < 4096; i += 1024)
    *(float4*)&Qs[i] = *(const float4*)&Qg[(size_t)cid * 4096 + i];
  float Cr[32], Ci[32];
#pragma unroll
  for (int bk = 0; bk < 32; ++bk) {
    const float2 cc = *(const float2*)&Cg[(((size_t)cid * 32 + bk) * 64 + lane) * 2];
    Cr[bk] = cc.x; Ci[bk] = cc.y;
  }
  __syncthreads();
  const int m0 = b * 2048 + c * 64;
  for (int tt = 0; tt < 16; ++tt) {
    const int t = wv * 16 + tt;
    float y = yi[(size_t)cid * 4096 + t * 64 + lane];
#pragma unroll
    for (int bk = 0; bk < 32; ++bk) {
      const float2 a = *(const float2*)&Qs[t * 64 + 2 * bk];   // LDS broadcast
      y = fmaf(a.x, Cr[bk], y);
      y = fmaf(-a.y, Ci[bk], y);
    }
    attn[(size_t)(m0 + t) * 1024 + h * 64 + lane] = f2bf(y);
  }
}

// ---------------------------------------------------------------------------
extern "C" void kernel_launch(void* const* d_in, const int* in_sizes, int n_in,
                              void* d_out, int out_size, void* d_ws, size_t ws_size,
                              hipStream_t stream) {
  const float* x   = (const float*)d_in[0];
  const float* Wq  = (const float*)d_in[1];
  const float* bq  = (const float*)d_in[2];
  const float* Wk  = (const float*)d_in[3];
  const float* bk_ = (const float*)d_in[4];
  const float* Wv  = (const float*)d_in[5];
  const float* bv  = (const float*)d_in[6];
  const float* Wo  = (const float*)d_in[7];
  const float* bo  = (const float*)d_in[8];
  const float* n1g = (const float*)d_in[9];
  const float* n1b = (const float*)d_in[10];
  const float* n2g = (const float*)d_in[11];
  const float* n2b = (const float*)d_in[12];
  const float* thb = (const float*)d_in[13];
  const float* tw1 = (const float*)d_in[14];
  const float* tw2 = (const float*)d_in[15];
  const float* lamb= (const float*)d_in[16];
  const float* eta = (const float*)d_in[17];
  const float* Wf1 = (const float*)d_in[18];
  const float* bf1 = (const float*)d_in[19];
  const float* Wf2 = (const float*)d_in[20];
  const float* bf2 = (const float*)d_in[21];

  char* ws = (char*)d_ws;
  size_t off = 0;
  auto alloc = [&](size_t bytes) {
    size_t r = off;
    off += (bytes + 255) & ~(size_t)255;
    return r;
  };
  unsigned short* WCAT = (unsigned short*)(ws + alloc(3200ull * 1024 * 2));
  unsigned short* WOT  = (unsigned short*)(ws + alloc(1024ull * 1024 * 2));
  unsigned short* WF1T = (unsigned short*)(ws + alloc(4096ull * 1024 * 2));
  unsigned short* WF2T = (unsigned short*)(ws + alloc(1024ull * 4096 * 2));
  float* BIASC = (float*)(ws + alloc(3200ull * 4));
  unsigned short* XN = (unsigned short*)(ws + alloc(8192ull * 1024 * 2));  // also H (ln2 out)
  char* QKVbase = ws + alloc(8192ull * 3200 * 4);
  float* QKV = (float*)QKVbase;
  unsigned short* GBUF = (unsigned short*)QKVbase;              // FFN1 out (after passA)
  float* CG = (float*)(QKVbase + 8192ull * 4096 * 2);           // scan out (tail alias)
  float* THETA = (float*)(ws + alloc(8192ull * 512 * 4));       // also ATTN bf16 (after passA)
  unsigned short* ATTN = (unsigned short*)THETA;
  float* YI = (float*)(ws + alloc(2048ull * 64 * 64 * 4));      // also X1 (after passC)
  float* X1 = YI;
  float* QG = (float*)(ws + alloc(2048ull * 64 * 64 * 4));
  float* TG = (float*)(ws + alloc(2048ull * 32 * 64 * 2 * 4));
  float* DG = (float*)(ws + alloc(2048ull * 32 * 2 * 4));

  if (ws_size < off) {
    fill_kernel<<<dim3((out_size + 255) / 256), dim3(256), 0, stream>>>((float*)d_out, 12345.0f, out_size);
    return;
  }

  const dim3 b256(256), b32x8(32, 8);

  // weight prep
  prep_wcat<<<dim3(100, 32), b32x8, 0, stream>>>(Wq, Wk, Wv, tw1, WCAT);
  transpose_bf16<<<dim3(32, 32), b32x8, 0, stream>>>(Wo, WOT, 1024, 1024);
  transpose_bf16<<<dim3(128, 32), b32x8, 0, stream>>>(Wf1, WF1T, 1024, 4096);
  transpose_bf16<<<dim3(32, 128), b32x8, 0, stream>>>(Wf2, WF2T, 4096, 1024);
  biascat_kernel<<<dim3(13), b256, 0, stream>>>(bq, bk_, bv, BIASC);

  // LN1 -> xn (bf16)
  ln_kernel<<<dim3(8192), b256, 0, stream>>>(x, n1g, n1b, XN);
  // QKV + lora1
  gemm_kernel<0><<<dim3(25, 64), b256, 0, stream>>>(XN, WCAT, BIASC, nullptr, QKV, 3200, 1024);
  // lora2 -> theta
  lora2_kernel<<<dim3(256), b256, 0, stream>>>(QKV, tw2, thb, THETA);
  // attention passes
  passA_kernel<<<dim3(32, 64), b256, 0, stream>>>(QKV, THETA, lamb, eta, YI, QG, TG, DG);
  scanB_kernel<<<dim3(64), b256, 0, stream>>>(TG, DG, CG);
  passC_kernel<<<dim3(32, 64), b256, 0, stream>>>(YI, QG, CG, ATTN);
  // x1 = x + attn@Wo + bo
  gemm_kernel<1><<<dim3(8, 64), b256, 0, stream>>>(ATTN, WOT, bo, x, X1, 1024, 1024);
  // LN2 -> h (bf16)
  ln_kernel<<<dim3(8192), b256, 0, stream>>>(X1, n2g, n2b, XN);
  // FFN1
  gemm_kernel<2><<<dim3(32, 64), b256, 0, stream>>>(XN, WF1T, bf1, nullptr, GBUF, 4096, 1024);
  // FFN2
  gemm_kernel<1><<<dim3(8, 64), b256, 0, stream>>>(GBUF, WF2T, bf2, X1, d_out, 1024, 4096);
}

// Round 3
// 634.068 us; speedup vs baseline: 1.2403x; 1.2403x over previous
//
#include <hip/hip_runtime.h>

// ---------------------------------------------------------------------------
// CausalLinearAttentionRSEEncoder — MFMA chunked formulation (subchunk = 16)
// B=4 T=2048 D=1024 H=16 K=64 BK=32 FFN=4096 LORA=48  NSUB=128 per (b,h)
// ---------------------------------------------------------------------------

typedef __bf16 bf16x8 __attribute__((ext_vector_type(8)));
typedef float f32x4 __attribute__((ext_vector_type(4)));

__device__ __forceinline__ unsigned short f2bf(float f) {
  unsigned int u = __builtin_bit_cast(unsigned int, f);
  u += 0x7FFFu + ((u >> 16) & 1u);
  return (unsigned short)(u >> 16);
}
__device__ __forceinline__ float bf2f(unsigned short u) {
  unsigned int x = ((unsigned int)u) << 16;
  return __builtin_bit_cast(float, x);
}
__device__ __forceinline__ unsigned int pack2(float a, float b) {
  return (unsigned int)f2bf(a) | ((unsigned int)f2bf(b) << 16);
}

__device__ __forceinline__ void gload_lds16(const void* g, void* l) {
  __builtin_amdgcn_global_load_lds((const __attribute__((address_space(1))) void*)g,
                                   (__attribute__((address_space(3))) void*)l, 16, 0, 0);
}

__device__ __forceinline__ float gelu_tanh(float v) {
  float c = fmaf(0.044715f * v * v, v, v);
  return 0.5f * v * (1.f + tanhf(0.7978845608028654f * c));
}

// -------------------------------- fill (ws guard) ---------------------------
__global__ void fill_kernel(float* p, float v, int n) {
  int i = blockIdx.x * 256 + threadIdx.x;
  if (i < n) p[i] = v;
}

// -------------------------------- LayerNorm -> bf16 -------------------------
__global__ __launch_bounds__(256) void ln_kernel(
    const float* __restrict__ x, const float* __restrict__ g,
    const float* __restrict__ b, unsigned short* __restrict__ out) {
  const int row = blockIdx.x, tid = threadIdx.x;
  float4 v = ((const float4*)(x + (size_t)row * 1024))[tid];
  float s = v.x + v.y + v.z + v.w;
  float sq = v.x * v.x + v.y * v.y + v.z * v.z + v.w * v.w;
#pragma unroll
  for (int o = 32; o > 0; o >>= 1) { s += __shfl_xor(s, o); sq += __shfl_xor(sq, o); }
  __shared__ float red[8];
  const int wid = tid >> 6;
  if ((tid & 63) == 0) { red[wid] = s; red[4 + wid] = sq; }
  __syncthreads();
  s = red[0] + red[1] + red[2] + red[3];
  sq = red[4] + red[5] + red[6] + red[7];
  const float mean = s * (1.f / 1024.f);
  const float var = sq * (1.f / 1024.f) - mean * mean;
  const float rstd = rsqrtf(var + 1e-6f);
  float4 gv = ((const float4*)g)[tid];
  float4 bvv = ((const float4*)b)[tid];
  ushort4 o4;
  o4.x = f2bf((v.x - mean) * rstd * gv.x + bvv.x);
  o4.y = f2bf((v.y - mean) * rstd * gv.y + bvv.y);
  o4.z = f2bf((v.z - mean) * rstd * gv.z + bvv.z);
  o4.w = f2bf((v.w - mean) * rstd * gv.w + bvv.w);
  *(ushort4*)(out + (size_t)row * 1024 + tid * 4) = o4;
}

// ------------------------- weight transposes to bf16 ------------------------
__global__ __launch_bounds__(256) void transpose_bf16(
    const float* __restrict__ src, unsigned short* __restrict__ dst, int K, int N) {
  __shared__ float tile[32][33];
  const int n0 = blockIdx.x * 32, k0 = blockIdx.y * 32;
  const int tx = threadIdx.x, ty = threadIdx.y;
#pragma unroll
  for (int j = 0; j < 32; j += 8) tile[tx][ty + j] = src[(size_t)(k0 + ty + j) * N + n0 + tx];
  __syncthreads();
#pragma unroll
  for (int j = 0; j < 32; j += 8)
    dst[(size_t)(n0 + ty + j) * K + k0 + tx] = f2bf(tile[ty + j][tx]);
}

// WcatT[3200][1024]
__global__ __launch_bounds__(256) void prep_wcat(
    const float* __restrict__ Wq, const float* __restrict__ Wk,
    const float* __restrict__ Wv, const float* __restrict__ tw1,
    unsigned short* __restrict__ dst) {
  __shared__ float tile[32][33];
  const int r0 = blockIdx.x * 32, c0 = blockIdx.y * 32;
  const int tx = threadIdx.x, ty = threadIdx.y;
  const int r = r0 + tx;
#pragma unroll
  for (int j = 0; j < 32; j += 8) {
    const int c = c0 + ty + j;
    float v;
    if (r < 1024) v = Wq[(size_t)c * 1024 + r];
    else if (r < 2048) v = Wk[(size_t)c * 1024 + (r - 1024)];
    else if (r < 3072) v = Wv[(size_t)c * 1024 + (r - 2048)];
    else if (r < 3120) v = tw1[(size_t)c * 48 + (r - 3072)];
    else v = 0.f;
    tile[tx][ty + j] = v;
  }
  __syncthreads();
#pragma unroll
  for (int j = 0; j < 32; j += 8)
    dst[(size_t)(r0 + ty + j) * 1024 + c0 + tx] = f2bf(tile[ty + j][tx]);
}

__global__ void biascat_kernel(const float* bq, const float* bk, const float* bv, float* dst) {
  int i = blockIdx.x * 256 + threadIdx.x;
  if (i >= 3200) return;
  float v = 0.f;
  if (i < 1024) v = bq[i];
  else if (i < 2048) v = bk[i - 1024];
  else if (i < 3072) v = bv[i - 2048];
  dst[i] = v;
}

// ------------------------------- bf16 MFMA GEMM -----------------------------
// MODE 0: fp32 out; 1: fp32 out + res; 2: bf16 out, gelu; 3: bf16 out plain
template <int MODE>
__global__ __launch_bounds__(256) void gemm_kernel(
    const unsigned short* __restrict__ A, const unsigned short* __restrict__ BT,
    const float* __restrict__ bias, const float* __restrict__ res,
    void* __restrict__ out, int N, int Kd) {
  __shared__ unsigned short As[128 * 64];
  __shared__ unsigned short Bs[128 * 64];
  const int n0 = blockIdx.x * 128, m0 = blockIdx.y * 128;
  const int tid = threadIdx.x, wv = tid >> 6, ln = tid & 63;
  const int wm = wv >> 1, wn = wv & 1;
  const int l15 = ln & 15, lk = (ln >> 4) * 8;
  const int rsub = ln >> 3;
  const int csub = (ln & 7) * 8;
  f32x4 acc[4][4] = {};
  for (int k0 = 0; k0 < Kd; k0 += 64) {
#pragma unroll
    for (int jj = 0; jj < 4; ++jj) {
      const int r0 = (wv * 4 + jj) * 8;
      gload_lds16(A + (size_t)(m0 + r0 + rsub) * Kd + k0 + csub,
                  (char*)As + (wv * 4 + jj) * 1024);
      gload_lds16(BT + (size_t)(n0 + r0 + rsub) * Kd + k0 + csub,
                  (char*)Bs + (wv * 4 + jj) * 1024);
    }
    __syncthreads();
#pragma unroll
    for (int kk = 0; kk < 64; kk += 32) {
      bf16x8 av[4], bv[4];
#pragma unroll
      for (int f = 0; f < 4; ++f) {
        av[f] = *(const bf16x8*)&As[(wm * 64 + f * 16 + l15) * 64 + kk + lk];
        bv[f] = *(const bf16x8*)&Bs[(wn * 64 + f * 16 + l15) * 64 + kk + lk];
      }
#pragma unroll
      for (int fm = 0; fm < 4; ++fm)
#pragma unroll
        for (int fn = 0; fn < 4; ++fn)
          acc[fm][fn] = __builtin_amdgcn_mfma_f32_16x16x32_bf16(av[fm], bv[fn], acc[fm][fn], 0, 0, 0);
    }
    __syncthreads();
  }
  const int rb = (ln >> 4) * 4;
#pragma unroll
  for (int fm = 0; fm < 4; ++fm) {
#pragma unroll
    for (int fn = 0; fn < 4; ++fn) {
      const int row = m0 + wm * 64 + fm * 16 + rb;
      const int col = n0 + wn * 64 + fn * 16 + l15;
      const float bval = bias[col];
#pragma unroll
      for (int r = 0; r < 4; ++r) {
        float v = acc[fm][fn][r] + bval;
        const size_t oi = (size_t)(row + r) * N + col;
        if constexpr (MODE == 1) v += res[oi];
        if constexpr (MODE == 2) {
          ((unsigned short*)out)[oi] = f2bf(gelu_tanh(v));
        } else if constexpr (MODE == 3) {
          ((unsigned short*)out)[oi] = f2bf(v);
        } else {
          ((float*)out)[oi] = v;
        }
      }
    }
  }
}

// -------------------------- LoRA2 + theta (clip) ----------------------------
__global__ __launch_bounds__(256) void lora2_kernel(
    const unsigned short* __restrict__ qkv, const float* __restrict__ w2,
    const float* __restrict__ tbase, float* __restrict__ theta) {
  __shared__ float lt[8][48];
  const int m0 = blockIdx.x * 32;
  const int tid = threadIdx.x;
  const int col = tid * 2;
  const float tb0 = tbase[col], tb1 = tbase[col + 1];
  for (int grp = 0; grp < 4; ++grp) {
    const int mg = m0 + grp * 8;
    __syncthreads();
    for (int idx = tid; idx < 384; idx += 256) {
      const int tok = idx / 48, jj = idx % 48;
      lt[tok][jj] = tanhf(bf2f(qkv[(size_t)(mg + tok) * 3200 + 3072 + jj]));
    }
    __syncthreads();
    float a0[8], a1[8];
#pragma unroll
    for (int tok = 0; tok < 8; ++tok) { a0[tok] = tb0; a1[tok] = tb1; }
    for (int jj = 0; jj < 48; ++jj) {
      const float2 w = *(const float2*)&w2[(size_t)jj * 512 + col];
#pragma unroll
      for (int tok = 0; tok < 8; ++tok) {
        const float l = lt[tok][jj];
        a0[tok] = fmaf(l, w.x, a0[tok]);
        a1[tok] = fmaf(l, w.y, a1[tok]);
      }
    }
    const float CL = 1.5707963267948966f;
#pragma unroll
    for (int tok = 0; tok < 8; ++tok) {
      float c0 = fminf(fmaxf(a0[tok], -CL), CL);
      float c1 = fminf(fmaxf(a1[tok], -CL), CL);
      *(float2*)&theta[(size_t)(mg + tok) * 512 + col] = make_float2(c0, c1);
    }
  }
}

// ------------------------------- attn_intra ---------------------------------
// Block = (chunk64 c, bh); wave wv = subchunk sc = c*4+wv (16 tokens).
// Per wave: prep qd/kd tiles (mid-referenced), G = Qd*Kd^T (masked),
// Y = G*V -> yi; T = KdE^T*V -> TCG; qd_glob -> QG; D -> Dg. All wave-private.
__global__ __launch_bounds__(256) void attn_intra(
    const unsigned short* __restrict__ qkv, const float* __restrict__ theta,
    const float* __restrict__ lamb, const float* __restrict__ eta,
    float* __restrict__ yi, unsigned short* __restrict__ QG,
    unsigned short* __restrict__ TCG, float* __restrict__ Dg) {
  const int c = blockIdx.x, bh = blockIdx.y;
  const int b = bh >> 4, h = bh & 15;
  const int tid = threadIdx.x, wv = tid >> 6, lane = tid & 63;
  const int sc = c * 4 + wv;
  const int cid = bh * 128 + sc;
  const int mw = b * 2048 + sc * 16;

  __shared__ unsigned short QDm[4][16][64];   // [t][2bk] packed qd_mid (swz)
  __shared__ unsigned short KDm[4][16][64];   // [s][2bk] packed {kd_r,-kd_i} (swz)
  __shared__ unsigned short KdET[4][64][32];  // rows 0-31 kdE_r[bk][s], 32-63 kdE_i; s>=16 zero
  __shared__ unsigned short VT[4][64][32];    // [v][s], s>=16 zero
  __shared__ unsigned short Gs[4][16][32];    // [t][s] masked G, s>=16 zero

  // zero K-padding regions (cols 16..31)
  {
    unsigned int* kz = (unsigned int*)&KdET[wv][0][0];
    unsigned int* vz = (unsigned int*)&VT[wv][0][0];
    for (int idx = lane; idx < 512; idx += 64) {
      const int r = idx >> 3, p = (idx & 7) + 8;
      kz[r * 16 + p] = 0; vz[r * 16 + p] = 0;
    }
    unsigned int* gz = (unsigned int*)&Gs[wv][0][0];
    for (int idx = lane; idx < 128; idx += 64) {
      const int r = idx >> 3, p = (idx & 7) + 8;
      gz[r * 16 + p] = 0;
    }
  }
  // VT fill (v already bf16 in qkv)
  for (int ss = 0; ss < 16; ++ss)
    VT[wv][lane][ss] = qkv[(size_t)(mw + ss) * 3200 + 2048 + h * 64 + lane];

  const int bk = lane & 31, th = lane >> 5;
  const float lb = lamb[h * 32 + bk], et = eta[h * 32 + bk];
  float L[8], Th[8], qr[8], qi[8], kr[8], ki[8];
  float runL = 0.f, runT = 0.f;
#pragma unroll
  for (int i = 0; i < 8; ++i) {
    const size_t m = (size_t)(mw + th * 8 + i);
    const float tv = theta[m * 512 + h * 32 + bk];
    const float lam = fmaf(et * tv, tv, lb);
    runL += lam; L[i] = runL;
    runT += tv;  Th[i] = runT;
    const unsigned int qp = *(const unsigned int*)&qkv[m * 3200 + h * 64 + 2 * bk];
    const unsigned int kp = *(const unsigned int*)&qkv[m * 3200 + 1024 + h * 64 + 2 * bk];
    qr[i] = bf2f((unsigned short)(qp & 0xFFFF)); qi[i] = bf2f((unsigned short)(qp >> 16));
    const float kx = bf2f((unsigned short)(kp & 0xFFFF));
    const float ky = bf2f((unsigned short)(kp >> 16));
    kr[i] = kx > 0.f ? kx + 1.f : __expf(kx);
    ki[i] = ky > 0.f ? ky + 1.f : __expf(ky);
  }
  const float oL = __shfl_xor(runL, 32), oT = __shfl_xor(runT, 32);
  const float Lm = th ? oL : runL;     // half-0 totals = mid reference
  const float Tm = th ? oT : runT;
  const float Ltot = runL + oL, Ttot = runT + oT;
  const float Lbase = th ? oL : 0.f, Tbase = th ? oT : 0.f;
  float Es, Ec; __sincosf(Tm, &Es, &Ec);
  const float Ee = __expf(-Lm);
  const float Er = Ee * Ec, Ei = Ee * Es;             // E = exp(-Lm + j Tm)
  float Fs, Fc; __sincosf(Ttot - Tm, &Fs, &Fc);
  const float Fe = __expf(-(Ltot - Lm));
  const float Fr = Fe * Fc, Fi = Fe * Fs;             // F = exp(-(Ltot-Lm)+j(Ttot-Tm))
  if (th == 0) {
    float Ds, Dc; __sincosf(Ttot, &Ds, &Dc);
    const float De = __expf(-Ltot);
    *(float2*)&Dg[((size_t)cid * 32 + bk) * 2] = make_float2(De * Dc, De * Ds);
  }
  unsigned int* qd32 = (unsigned int*)&QDm[wv][0][0];
  unsigned int* kd32 = (unsigned int*)&KDm[wv][0][0];
#pragma unroll
  for (int i = 0; i < 8; ++i) {
    const int t = th * 8 + i;
    const float Lg = Lbase + L[i], Tg = Tbase + Th[i];
    const float dm = __expf(-(Lg - Lm));               // e^{±55} max
    float sn, cs; __sincosf(Tg - Tm, &sn, &cs);
    const float qmr = dm * (qr[i] * cs + qi[i] * sn);
    const float qmi = dm * (qr[i] * sn - qi[i] * cs);
    const float rd = 1.f / dm;
    const float kmr = rd * (kr[i] * cs + ki[i] * sn);
    const float kmi = rd * (ki[i] * cs - kr[i] * sn);
    const int sidx = (t * 32 + bk) ^ ((t & 7) << 2);   // XOR swizzle (u32 units)
    qd32[sidx] = pack2(qmr, qmi);
    kd32[sidx] = pack2(kmr, -kmi);
    // qd_glob = qd_mid * E  -> QG
    ((unsigned int*)QG)[(size_t)cid * 512 + t * 32 + bk] =
        pack2(qmr * Er - qmi * Ei, qmr * Ei + qmi * Er);
    // kdE = kd_mid * F -> KdET (transposed rows)
    const float er = kmr * Fr - kmi * Fi;
    const float ei = kmr * Fi + kmi * Fr;
    KdET[wv][bk][t] = f2bf(er);
    KdET[wv][32 + bk][t] = f2bf(ei);
  }

  // ---- MFMA phase (wave-private LDS; compiler inserts lgkm waits) ----
  const int l15 = lane & 15, hi = lane >> 4;
  const char* qb = (const char*)&QDm[wv][0][0];
  const char* kb = (const char*)&KDm[wv][0][0];
  f32x4 z = {};
  f32x4 g = z;
  {
    bf16x8 a0 = *(const bf16x8*)(qb + l15 * 128 + ((16 * hi) ^ ((l15 & 7) << 4)));
    bf16x8 b0 = *(const bf16x8*)(kb + l15 * 128 + ((16 * hi) ^ ((l15 & 7) << 4)));
    bf16x8 a1 = *(const bf16x8*)(qb + l15 * 128 + ((64 + 16 * hi) ^ ((l15 & 7) << 4)));
    bf16x8 b1 = *(const bf16x8*)(kb + l15 * 128 + ((64 + 16 * hi) ^ ((l15 & 7) << 4)));
    g = __builtin_amdgcn_mfma_f32_16x16x32_bf16(a0, b0, g, 0, 0, 0);
    g = __builtin_amdgcn_mfma_f32_16x16x32_bf16(a1, b1, g, 0, 0, 0);
  }
#pragma unroll
  for (int r = 0; r < 4; ++r) {
    const float gv = (l15 <= 4 * hi + r) ? g[r] : 0.f;  // tril mask (incl diag)
    Gs[wv][4 * hi + r][l15] = f2bf(gv);
  }
  const char* gsb = (const char*)&Gs[wv][0][0];
  const char* vtb = (const char*)&VT[wv][0][0];
  bf16x8 aG = *(const bf16x8*)(gsb + l15 * 64 + 16 * hi);
#pragma unroll
  for (int nt = 0; nt < 4; ++nt) {
    bf16x8 bV = *(const bf16x8*)(vtb + (nt * 16 + l15) * 64 + 16 * hi);
    f32x4 y = __builtin_amdgcn_mfma_f32_16x16x32_bf16(aG, bV, z, 0, 0, 0);
#pragma unroll
    for (int r = 0; r < 4; ++r)
      yi[(size_t)cid * 1024 + (4 * hi + r) * 64 + nt * 16 + l15] = y[r];
  }
  const char* keb = (const char*)&KdET[wv][0][0];
#pragma unroll
  for (int mt = 0; mt < 4; ++mt) {
    bf16x8 aT = *(const bf16x8*)(keb + (mt * 16 + l15) * 64 + 16 * hi);
#pragma unroll
    for (int nt = 0; nt < 4; ++nt) {
      bf16x8 bV = *(const bf16x8*)(vtb + (nt * 16 + l15) * 64 + 16 * hi);
      f32x4 t4 = __builtin_amdgcn_mfma_f32_16x16x32_bf16(aT, bV, z, 0, 0, 0);
#pragma unroll
      for (int r = 0; r < 4; ++r)
        TCG[(size_t)cid * 4096 + (mt * 16 + 4 * hi + r) * 64 + nt * 16 + l15] = f2bf(t4[r]);
    }
  }
}

// ------------------------------- scanB --------------------------------------
// Per bh: C[0]=0; iterate 128 subchunks: read T[c] (bf16), barrier, write
// Cpack[c] IN-PLACE into TCG ([v][2bk] = {C_r, -C_i}), update C = D*C + T.
__global__ __launch_bounds__(256) void scanB_kernel(
    unsigned short* __restrict__ TCG, const float* __restrict__ Dg) {
  const int bh = blockIdx.x;
  const int tid = threadIdx.x, wv = tid >> 6, lane = tid & 63;
  const int bkb = wv * 8;
  float Cr[8], Ci[8];
#pragma unroll
  for (int i = 0; i < 8; ++i) { Cr[i] = 0.f; Ci[i] = 0.f; }
  for (int c0 = 0; c0 < 128; c0 += 2) {
    float tr[2][8], ti[2][8]; float2 dv[2][8];
#pragma unroll
    for (int u = 0; u < 2; ++u) {
      const size_t cid = (size_t)bh * 128 + c0 + u;
#pragma unroll
      for (int i = 0; i < 8; ++i) {
        tr[u][i] = bf2f(TCG[cid * 4096 + (bkb + i) * 64 + lane]);
        ti[u][i] = bf2f(TCG[cid * 4096 + (32 + bkb + i) * 64 + lane]);
        dv[u][i] = *(const float2*)&Dg[(cid * 32 + bkb + i) * 2];
      }
    }
    __syncthreads();  // all reads of T[c0..c0+1] done before overwrite
#pragma unroll
    for (int u = 0; u < 2; ++u) {
      const size_t cid = (size_t)bh * 128 + c0 + u;
#pragma unroll
      for (int i = 0; i < 8; ++i) {
        ((unsigned int*)TCG)[cid * 2048 + (size_t)lane * 32 + bkb + i] = pack2(Cr[i], -Ci[i]);
        const float nr = fmaf(dv[u][i].x, Cr[i], fmaf(-dv[u][i].y, Ci[i], tr[u][i]));
        const float ni = fmaf(dv[u][i].x, Ci[i], fmaf(dv[u][i].y, Cr[i], ti[u][i]));
        Cr[i] = nr; Ci[i] = ni;
      }
    }
  }
}

// ------------------------------- attn_cross ---------------------------------
// y = yi + QdG[16x64] @ CpackT[64v][64kk]^T  -> attn bf16 [m][h*64+v]
__global__ __launch_bounds__(256) void attn_cross(
    const float* __restrict__ yi, const unsigned short* __restrict__ QG,
    const unsigned short* __restrict__ TCG, unsigned short* __restrict__ attn) {
  const int c = blockIdx.x, bh = blockIdx.y;
  const int b = bh >> 4, h = bh & 15;
  const int tid = threadIdx.x, wv = tid >> 6, lane = tid & 63;
  const int sc = c * 4 + wv, cid = bh * 128 + sc;
  const int mw = b * 2048 + sc * 16;
  __shared__ unsigned short Cp[4][64][64];
  __shared__ unsigned short Qs[4][16][64];
  unsigned int* cp32 = (unsigned int*)&Cp[wv][0][0];
  const unsigned int* cg = (const unsigned int*)TCG + (size_t)cid * 2048;
  for (int ii = 0; ii < 32; ++ii) {
    const int flat = ii * 64 + lane;
    const int row = flat >> 5, col = flat & 31;
    cp32[(row * 32 + col) ^ ((row & 7) << 2)] = cg[flat];
  }
  unsigned int* qs32 = (unsigned int*)&Qs[wv][0][0];
  const unsigned int* qg = (const unsigned int*)QG + (size_t)cid * 512;
  for (int ii = 0; ii < 8; ++ii) {
    const int flat = ii * 64 + lane;
    const int row = flat >> 5, col = flat & 31;
    qs32[(row * 32 + col) ^ ((row & 7) << 2)] = qg[flat];
  }
  const int l15 = lane & 15, hi = lane >> 4;
  const char* qb = (const char*)&Qs[wv][0][0];
  const char* cb = (const char*)&Cp[wv][0][0];
  bf16x8 a0 = *(const bf16x8*)(qb + l15 * 128 + ((16 * hi) ^ ((l15 & 7) << 4)));
  bf16x8 a1 = *(const bf16x8*)(qb + l15 * 128 + ((64 + 16 * hi) ^ ((l15 & 7) << 4)));
  f32x4 z = {};
#pragma unroll
  for (int nt = 0; nt < 4; ++nt) {
    const int vr = nt * 16 + l15;
    bf16x8 b0 = *(const bf16x8*)(cb + vr * 128 + ((16 * hi) ^ ((vr & 7) << 4)));
    bf16x8 b1 = *(const bf16x8*)(cb + vr * 128 + ((64 + 16 * hi) ^ ((vr & 7) << 4)));
    f32x4 y = __builtin_amdgcn_mfma_f32_16x16x32_bf16(a0, b0, z, 0, 0, 0);
    y = __builtin_amdgcn_mfma_f32_16x16x32_bf16(a1, b1, y, 0, 0, 0);
#pragma unroll
    for (int r = 0; r < 4; ++r) {
      const int t = 4 * hi + r;
      const float out = y[r] + yi[(size_t)cid * 1024 + t * 64 + vr];
      attn[(size_t)(mw + t) * 1024 + h * 64 + vr] = f2bf(out);
    }
  }
}

// ---------------------------------------------------------------------------
extern "C" void kernel_launch(void* const* d_in, const int* in_sizes, int n_in,
                              void* d_out, int out_size, void* d_ws, size_t ws_size,
                              hipStream_t stream) {
  const float* x   = (const float*)d_in[0];
  const float* Wq  = (const float*)d_in[1];
  const float* bq  = (const float*)d_in[2];
  const float* Wk  = (const float*)d_in[3];
  const float* bk_ = (const float*)d_in[4];
  const float* Wv  = (const float*)d_in[5];
  const float* bv  = (const float*)d_in[6];
  const float* Wo  = (const float*)d_in[7];
  const float* bo  = (const float*)d_in[8];
  const float* n1g = (const float*)d_in[9];
  const float* n1b = (const float*)d_in[10];
  const float* n2g = (const float*)d_in[11];
  const float* n2b = (const float*)d_in[12];
  const float* thb = (const float*)d_in[13];
  const float* tw1 = (const float*)d_in[14];
  const float* tw2 = (const float*)d_in[15];
  const float* lamb= (const float*)d_in[16];
  const float* eta = (const float*)d_in[17];
  const float* Wf1 = (const float*)d_in[18];
  const float* bf1 = (const float*)d_in[19];
  const float* Wf2 = (const float*)d_in[20];
  const float* bf2 = (const float*)d_in[21];

  char* ws = (char*)d_ws;
  size_t off = 0;
  auto alloc = [&](size_t bytes) {
    size_t r = off;
    off += (bytes + 255) & ~(size_t)255;
    return r;
  };
  unsigned short* WCAT = (unsigned short*)(ws + alloc(3200ull * 1024 * 2));
  unsigned short* WOT  = (unsigned short*)(ws + alloc(1024ull * 1024 * 2));
  unsigned short* WF1T = (unsigned short*)(ws + alloc(4096ull * 1024 * 2));
  unsigned short* WF2T = (unsigned short*)(ws + alloc(1024ull * 4096 * 2));
  float* BIASC = (float*)(ws + alloc(3200ull * 4));
  unsigned short* XN = (unsigned short*)(ws + alloc(8192ull * 1024 * 2));  // also LN2 out
  char* QKVbase = ws + alloc(8192ull * 4096 * 2);   // QKV bf16 (52.4MB) / GBUF (67MB)
  unsigned short* QKV = (unsigned short*)QKVbase;
  unsigned short* GBUF = (unsigned short*)QKVbase;
  float* THETA = (float*)(ws + alloc(8192ull * 512 * 4));   // also ATTN bf16
  unsigned short* ATTN = (unsigned short*)THETA;
  float* YI = (float*)(ws + alloc(8192ull * 1024 * 4));     // also X1
  float* X1 = YI;
  unsigned short* QG = (unsigned short*)(ws + alloc(8192ull * 1024 * 2));
  unsigned short* TCG = (unsigned short*)(ws + alloc(8192ull * 4096 * 2)); // T then Cpack
  float* DG = (float*)(ws + alloc(8192ull * 32 * 2 * 4));

  if (ws_size < off) {
    fill_kernel<<<dim3((out_size + 255) / 256), dim3(256), 0, stream>>>((float*)d_out, 12345.0f, out_size);
    return;
  }

  const dim3 b256(256), b32x8(32, 8);

  // weight prep
  prep_wcat<<<dim3(100, 32), b32x8, 0, stream>>>(Wq, Wk, Wv, tw1, WCAT);
  transpose_bf16<<<dim3(32, 32), b32x8, 0, stream>>>(Wo, WOT, 1024, 1024);
  transpose_bf16<<<dim3(128, 32), b32x8, 0, stream>>>(Wf1, WF1T, 1024, 4096);
  transpose_bf16<<<dim3(32, 128), b32x8, 0, stream>>>(Wf2, WF2T, 4096, 1024);
  biascat_kernel<<<dim3(13), b256, 0, stream>>>(bq, bk_, bv, BIASC);

  // LN1 -> xn (bf16)
  ln_kernel<<<dim3(8192), b256, 0, stream>>>(x, n1g, n1b, XN);
  // QKV + lora1 (bf16 out)
  gemm_kernel<3><<<dim3(25, 64), b256, 0, stream>>>(XN, WCAT, BIASC, nullptr, QKV, 3200, 1024);
  // lora2 -> theta
  lora2_kernel<<<dim3(256), b256, 0, stream>>>(QKV, tw2, thb, THETA);
  // attention
  attn_intra<<<dim3(32, 64), b256, 0, stream>>>(QKV, THETA, lamb, eta, YI, QG, TCG, DG);
  scanB_kernel<<<dim3(64), b256, 0, stream>>>(TCG, DG);
  attn_cross<<<dim3(32, 64), b256, 0, stream>>>(YI, QG, TCG, ATTN);
  // x1 = x + attn@Wo + bo
  gemm_kernel<1><<<dim3(8, 64), b256, 0, stream>>>(ATTN, WOT, bo, x, X1, 1024, 1024);
  // LN2
  ln_kernel<<<dim3(8192), b256, 0, stream>>>(X1, n2g, n2b, XN);
  // FFN1 (gelu, bf16 out)
  gemm_kernel<2><<<dim3(32, 64), b256, 0, stream>>>(XN, WF1T, bf1, nullptr, GBUF, 4096, 1024);
  // FFN2 (+X1 residual, fp32 out)
  gemm_kernel<1><<<dim3(8, 64), b256, 0, stream>>>(GBUF, WF2T, bf2, X1, d_out, 1024, 4096);
}

// Round 4
// 526.542 us; speedup vs baseline: 1.4935x; 1.2042x over previous
//
#include <hip/hip_runtime.h>

// ---------------------------------------------------------------------------
// CausalLinearAttentionRSEEncoder — MFMA chunked formulation (subchunk = 16)
// B=4 T=2048 D=1024 H=16 K=64 BK=32 FFN=4096 LORA=48  NSUB=128 per (b,h)
// ---------------------------------------------------------------------------

typedef __bf16 bf16x8 __attribute__((ext_vector_type(8)));
typedef float f32x4 __attribute__((ext_vector_type(4)));

__device__ __forceinline__ unsigned short f2bf(float f) {
  unsigned int u = __builtin_bit_cast(unsigned int, f);
  u += 0x7FFFu + ((u >> 16) & 1u);
  return (unsigned short)(u >> 16);
}
__device__ __forceinline__ float bf2f(unsigned short u) {
  unsigned int x = ((unsigned int)u) << 16;
  return __builtin_bit_cast(float, x);
}
__device__ __forceinline__ unsigned int pack2(float a, float b) {
  return (unsigned int)f2bf(a) | ((unsigned int)f2bf(b) << 16);
}

__device__ __forceinline__ void gload_lds16(const void* g, void* l) {
  __builtin_amdgcn_global_load_lds((const __attribute__((address_space(1))) void*)g,
                                   (__attribute__((address_space(3))) void*)l, 16, 0, 0);
}

__device__ __forceinline__ float gelu_tanh(float v) {
  const float z = 0.7978845608028654f * fmaf(0.044715f * v * v, v, v);
  const float e = __expf(2.f * z);
  return 0.5f * v * (2.f - 2.f / (1.f + e));  // 0.5*v*(1+tanh(z))
}

// -------------------------------- fill (ws guard) ---------------------------
__global__ void fill_kernel(float* p, float v, int n) {
  int i = blockIdx.x * 256 + threadIdx.x;
  if (i < n) p[i] = v;
}

// -------------------------------- LayerNorm -> bf16 -------------------------
__global__ __launch_bounds__(256) void ln_kernel(
    const float* __restrict__ x, const float* __restrict__ g,
    const float* __restrict__ b, unsigned short* __restrict__ out) {
  const int row = blockIdx.x, tid = threadIdx.x;
  float4 v = ((const float4*)(x + (size_t)row * 1024))[tid];
  float s = v.x + v.y + v.z + v.w;
  float sq = v.x * v.x + v.y * v.y + v.z * v.z + v.w * v.w;
#pragma unroll
  for (int o = 32; o > 0; o >>= 1) { s += __shfl_xor(s, o); sq += __shfl_xor(sq, o); }
  __shared__ float red[8];
  const int wid = tid >> 6;
  if ((tid & 63) == 0) { red[wid] = s; red[4 + wid] = sq; }
  __syncthreads();
  s = red[0] + red[1] + red[2] + red[3];
  sq = red[4] + red[5] + red[6] + red[7];
  const float mean = s * (1.f / 1024.f);
  const float var = sq * (1.f / 1024.f) - mean * mean;
  const float rstd = rsqrtf(var + 1e-6f);
  float4 gv = ((const float4*)g)[tid];
  float4 bvv = ((const float4*)b)[tid];
  ushort4 o4;
  o4.x = f2bf((v.x - mean) * rstd * gv.x + bvv.x);
  o4.y = f2bf((v.y - mean) * rstd * gv.y + bvv.y);
  o4.z = f2bf((v.z - mean) * rstd * gv.z + bvv.z);
  o4.w = f2bf((v.w - mean) * rstd * gv.w + bvv.w);
  *(ushort4*)(out + (size_t)row * 1024 + tid * 4) = o4;
}

// ------------------------- weight transposes to bf16 ------------------------
__global__ __launch_bounds__(256) void transpose_bf16(
    const float* __restrict__ src, unsigned short* __restrict__ dst, int K, int N) {
  __shared__ float tile[32][33];
  const int n0 = blockIdx.x * 32, k0 = blockIdx.y * 32;
  const int tx = threadIdx.x, ty = threadIdx.y;
#pragma unroll
  for (int j = 0; j < 32; j += 8) tile[tx][ty + j] = src[(size_t)(k0 + ty + j) * N + n0 + tx];
  __syncthreads();
#pragma unroll
  for (int j = 0; j < 32; j += 8)
    dst[(size_t)(n0 + ty + j) * K + k0 + tx] = f2bf(tile[ty + j][tx]);
}

// WcatT[3200][1024]
__global__ __launch_bounds__(256) void prep_wcat(
    const float* __restrict__ Wq, const float* __restrict__ Wk,
    const float* __restrict__ Wv, const float* __restrict__ tw1,
    unsigned short* __restrict__ dst) {
  __shared__ float tile[32][33];
  const int r0 = blockIdx.x * 32, c0 = blockIdx.y * 32;
  const int tx = threadIdx.x, ty = threadIdx.y;
  const int r = r0 + tx;
#pragma unroll
  for (int j = 0; j < 32; j += 8) {
    const int c = c0 + ty + j;
    float v;
    if (r < 1024) v = Wq[(size_t)c * 1024 + r];
    else if (r < 2048) v = Wk[(size_t)c * 1024 + (r - 1024)];
    else if (r < 3072) v = Wv[(size_t)c * 1024 + (r - 2048)];
    else if (r < 3120) v = tw1[(size_t)c * 48 + (r - 3072)];
    else v = 0.f;
    tile[tx][ty + j] = v;
  }
  __syncthreads();
#pragma unroll
  for (int j = 0; j < 32; j += 8)
    dst[(size_t)(r0 + ty + j) * 1024 + c0 + tx] = f2bf(tile[ty + j][tx]);
}

__global__ void biascat_kernel(const float* bq, const float* bk, const float* bv, float* dst) {
  int i = blockIdx.x * 256 + threadIdx.x;
  if (i >= 3200) return;
  float v = 0.f;
  if (i < 1024) v = bq[i];
  else if (i < 2048) v = bk[i - 1024];
  else if (i < 3072) v = bv[i - 2048];
  dst[i] = v;
}

// ------------------------------- bf16 MFMA GEMM -----------------------------
// Pipelined 2-phase (T3-minimum): stage(t+1) issued before compute(t); single
// counted drain + raw barrier per K-tile. LDS chunk-permuted (conflict-free).
// MODE 0: fp32 out; 1: fp32 out + res; 2: bf16 out, gelu; 3: bf16 out plain
template <int MODE>
__global__ __launch_bounds__(256) void gemm_kernel(
    const unsigned short* __restrict__ A, const unsigned short* __restrict__ BT,
    const float* __restrict__ bias, const float* __restrict__ res,
    void* __restrict__ out, int N, int Kd) {
  __shared__ unsigned short As[2][128 * 64];
  __shared__ unsigned short Bs[2][128 * 64];
  // XCD-aware bijective swizzle (all grids have nwg % 8 == 0)
  const int nwg = gridDim.x * gridDim.y;
  int d = blockIdx.y * gridDim.x + blockIdx.x;
  d = (d & 7) * (nwg >> 3) + (d >> 3);
  const int n0 = (d % gridDim.x) * 128, m0 = (d / gridDim.x) * 128;

  const int tid = threadIdx.x, wv = tid >> 6, ln = tid & 63;
  const int wm = wv >> 1, wn = wv & 1;
  const int l15 = ln & 15, hi4 = ln >> 4;
  // staging geometry: slot = row*8 + (kg ^ (row&7)); issue (wv,jj) covers
  // slots jj*256+wv*64+lane -> row = jj*32 + wv*8 + (lane>>3), kg below.
  const int rbase = wv * 8 + (ln >> 3);
  const int kgofs = ((ln & 7) ^ ((ln >> 3) & 7)) * 8;   // element offset

  auto STAGE = [&](int buf, int k0) {
#pragma unroll
    for (int jj = 0; jj < 4; ++jj) {
      gload_lds16(A + (size_t)(m0 + jj * 32 + rbase) * Kd + k0 + kgofs,
                  (char*)&As[buf][0] + (jj * 256 + wv * 64) * 16);
      gload_lds16(BT + (size_t)(n0 + jj * 32 + rbase) * Kd + k0 + kgofs,
                  (char*)&Bs[buf][0] + (jj * 256 + wv * 64) * 16);
    }
  };

  f32x4 acc[4][4] = {};
  const int nt = Kd >> 6;
  STAGE(0, 0);
  asm volatile("s_waitcnt vmcnt(0)" ::: "memory");
  __builtin_amdgcn_s_barrier();
  __builtin_amdgcn_sched_barrier(0);
  int cur = 0;
  for (int t = 0; t < nt; ++t) {
    if (t + 1 < nt) STAGE(cur ^ 1, (t + 1) << 6);
    const unsigned short* Ac = &As[cur][0];
    const unsigned short* Bc = &Bs[cur][0];
#pragma unroll
    for (int kk = 0; kk < 64; kk += 32) {
      const int kg = (kk >> 3) + hi4;
      bf16x8 av[4], bv[4];
#pragma unroll
      for (int f = 0; f < 4; ++f) {
        const int ra = wm * 64 + f * 16 + l15;
        const int rb2 = wn * 64 + f * 16 + l15;
        av[f] = *(const bf16x8*)&Ac[(ra * 8 + (kg ^ (ra & 7))) * 8];
        bv[f] = *(const bf16x8*)&Bc[(rb2 * 8 + (kg ^ (rb2 & 7))) * 8];
      }
#pragma unroll
      for (int fm = 0; fm < 4; ++fm)
#pragma unroll
        for (int fn = 0; fn < 4; ++fn)
          acc[fm][fn] = __builtin_amdgcn_mfma_f32_16x16x32_bf16(av[fm], bv[fn], acc[fm][fn], 0, 0, 0);
    }
    if (t + 1 < nt) {
      __builtin_amdgcn_sched_barrier(0);
      asm volatile("s_waitcnt vmcnt(0)" ::: "memory");
      __builtin_amdgcn_s_barrier();
      __builtin_amdgcn_sched_barrier(0);
      cur ^= 1;
    }
  }
  const int rb = hi4 * 4;
#pragma unroll
  for (int fm = 0; fm < 4; ++fm) {
#pragma unroll
    for (int fn = 0; fn < 4; ++fn) {
      const int row = m0 + wm * 64 + fm * 16 + rb;
      const int col = n0 + wn * 64 + fn * 16 + l15;
      const float bval = bias[col];
#pragma unroll
      for (int r = 0; r < 4; ++r) {
        float v = acc[fm][fn][r] + bval;
        const size_t oi = (size_t)(row + r) * N + col;
        if constexpr (MODE == 1) v += res[oi];
        if constexpr (MODE == 2) {
          ((unsigned short*)out)[oi] = f2bf(gelu_tanh(v));
        } else if constexpr (MODE == 3) {
          ((unsigned short*)out)[oi] = f2bf(v);
        } else {
          ((float*)out)[oi] = v;
        }
      }
    }
  }
}

// -------------------------- LoRA2 + theta (clip) ----------------------------
__global__ __launch_bounds__(256) void lora2_kernel(
    const unsigned short* __restrict__ qkv, const float* __restrict__ w2,
    const float* __restrict__ tbase, float* __restrict__ theta) {
  __shared__ float lt[8][48];
  const int m0 = blockIdx.x * 32;
  const int tid = threadIdx.x;
  const int col = tid * 2;
  const float tb0 = tbase[col], tb1 = tbase[col + 1];
  for (int grp = 0; grp < 4; ++grp) {
    const int mg = m0 + grp * 8;
    __syncthreads();
    for (int idx = tid; idx < 384; idx += 256) {
      const int tok = idx / 48, jj = idx % 48;
      lt[tok][jj] = tanhf(bf2f(qkv[(size_t)(mg + tok) * 3200 + 3072 + jj]));
    }
    __syncthreads();
    float a0[8], a1[8];
#pragma unroll
    for (int tok = 0; tok < 8; ++tok) { a0[tok] = tb0; a1[tok] = tb1; }
    for (int jj = 0; jj < 48; ++jj) {
      const float2 w = *(const float2*)&w2[(size_t)jj * 512 + col];
#pragma unroll
      for (int tok = 0; tok < 8; ++tok) {
        const float l = lt[tok][jj];
        a0[tok] = fmaf(l, w.x, a0[tok]);
        a1[tok] = fmaf(l, w.y, a1[tok]);
      }
    }
    const float CL = 1.5707963267948966f;
#pragma unroll
    for (int tok = 0; tok < 8; ++tok) {
      float c0 = fminf(fmaxf(a0[tok], -CL), CL);
      float c1 = fminf(fmaxf(a1[tok], -CL), CL);
      *(float2*)&theta[(size_t)(mg + tok) * 512 + col] = make_float2(c0, c1);
    }
  }
}

// ------------------------------- attn_intra ---------------------------------
__global__ __launch_bounds__(256) void attn_intra(
    const unsigned short* __restrict__ qkv, const float* __restrict__ theta,
    const float* __restrict__ lamb, const float* __restrict__ eta,
    float* __restrict__ yi, unsigned short* __restrict__ QG,
    unsigned short* __restrict__ TCG, float* __restrict__ Dg) {
  const int c = blockIdx.x, bh = blockIdx.y;
  const int b = bh >> 4, h = bh & 15;
  const int tid = threadIdx.x, wv = tid >> 6, lane = tid & 63;
  const int sc = c * 4 + wv;
  const int cid = bh * 128 + sc;
  const int mw = b * 2048 + sc * 16;

  __shared__ unsigned short QDm[4][16][64];
  __shared__ unsigned short KDm[4][16][64];
  __shared__ unsigned short KdET[4][64][32];
  __shared__ unsigned short VT[4][64][32];
  __shared__ unsigned short Gs[4][16][32];

  {
    unsigned int* kz = (unsigned int*)&KdET[wv][0][0];
    unsigned int* vz = (unsigned int*)&VT[wv][0][0];
    for (int idx = lane; idx < 512; idx += 64) {
      const int r = idx >> 3, p = (idx & 7) + 8;
      kz[r * 16 + p] = 0; vz[r * 16 + p] = 0;
    }
    unsigned int* gz = (unsigned int*)&Gs[wv][0][0];
    for (int idx = lane; idx < 128; idx += 64) {
      const int r = idx >> 3, p = (idx & 7) + 8;
      gz[r * 16 + p] = 0;
    }
  }
  for (int ss = 0; ss < 16; ++ss)
    VT[wv][lane][ss] = qkv[(size_t)(mw + ss) * 3200 + 2048 + h * 64 + lane];

  const int bk = lane & 31, th = lane >> 5;
  const float lb = lamb[h * 32 + bk], et = eta[h * 32 + bk];
  float L[8], Th[8], qr[8], qi[8], kr[8], ki[8];
  float runL = 0.f, runT = 0.f;
#pragma unroll
  for (int i = 0; i < 8; ++i) {
    const size_t m = (size_t)(mw + th * 8 + i);
    const float tv = theta[m * 512 + h * 32 + bk];
    const float lam = fmaf(et * tv, tv, lb);
    runL += lam; L[i] = runL;
    runT += tv;  Th[i] = runT;
    const unsigned int qp = *(const unsigned int*)&qkv[m * 3200 + h * 64 + 2 * bk];
    const unsigned int kp = *(const unsigned int*)&qkv[m * 3200 + 1024 + h * 64 + 2 * bk];
    qr[i] = bf2f((unsigned short)(qp & 0xFFFF)); qi[i] = bf2f((unsigned short)(qp >> 16));
    const float kx = bf2f((unsigned short)(kp & 0xFFFF));
    const float ky = bf2f((unsigned short)(kp >> 16));
    kr[i] = kx > 0.f ? kx + 1.f : __expf(kx);
    ki[i] = ky > 0.f ? ky + 1.f : __expf(ky);
  }
  const float oL = __shfl_xor(runL, 32), oT = __shfl_xor(runT, 32);
  const float Lm = th ? oL : runL;
  const float Tm = th ? oT : runT;
  const float Ltot = runL + oL, Ttot = runT + oT;
  const float Lbase = th ? oL : 0.f, Tbase = th ? oT : 0.f;
  float Es, Ec; __sincosf(Tm, &Es, &Ec);
  const float Ee = __expf(-Lm);
  const float Er = Ee * Ec, Ei = Ee * Es;
  float Fs, Fc; __sincosf(Ttot - Tm, &Fs, &Fc);
  const float Fe = __expf(-(Ltot - Lm));
  const float Fr = Fe * Fc, Fi = Fe * Fs;
  if (th == 0) {
    float Ds, Dc; __sincosf(Ttot, &Ds, &Dc);
    const float De = __expf(-Ltot);
    *(float2*)&Dg[((size_t)cid * 32 + bk) * 2] = make_float2(De * Dc, De * Ds);
  }
  unsigned int* qd32 = (unsigned int*)&QDm[wv][0][0];
  unsigned int* kd32 = (unsigned int*)&KDm[wv][0][0];
#pragma unroll
  for (int i = 0; i < 8; ++i) {
    const int t = th * 8 + i;
    const float Lg = Lbase + L[i], Tg = Tbase + Th[i];
    const float dm = __expf(-(Lg - Lm));
    float sn, cs; __sincosf(Tg - Tm, &sn, &cs);
    const float qmr = dm * (qr[i] * cs + qi[i] * sn);
    const float qmi = dm * (qr[i] * sn - qi[i] * cs);
    const float rd = 1.f / dm;
    const float kmr = rd * (kr[i] * cs + ki[i] * sn);
    const float kmi = rd * (ki[i] * cs - kr[i] * sn);
    const int sidx = (t * 32 + bk) ^ ((t & 7) << 2);
    qd32[sidx] = pack2(qmr, qmi);
    kd32[sidx] = pack2(kmr, -kmi);
    ((unsigned int*)QG)[(size_t)cid * 512 + t * 32 + bk] =
        pack2(qmr * Er - qmi * Ei, qmr * Ei + qmi * Er);
    const float er = kmr * Fr - kmi * Fi;
    const float ei = kmr * Fi + kmi * Fr;
    KdET[wv][bk][t] = f2bf(er);
    KdET[wv][32 + bk][t] = f2bf(ei);
  }

  const int l15 = lane & 15, hi = lane >> 4;
  const char* qb = (const char*)&QDm[wv][0][0];
  const char* kb = (const char*)&KDm[wv][0][0];
  f32x4 z = {};
  f32x4 g = z;
  {
    bf16x8 a0 = *(const bf16x8*)(qb + l15 * 128 + ((16 * hi) ^ ((l15 & 7) << 4)));
    bf16x8 b0 = *(const bf16x8*)(kb + l15 * 128 + ((16 * hi) ^ ((l15 & 7) << 4)));
    bf16x8 a1 = *(const bf16x8*)(qb + l15 * 128 + ((64 + 16 * hi) ^ ((l15 & 7) << 4)));
    bf16x8 b1 = *(const bf16x8*)(kb + l15 * 128 + ((64 + 16 * hi) ^ ((l15 & 7) << 4)));
    g = __builtin_amdgcn_mfma_f32_16x16x32_bf16(a0, b0, g, 0, 0, 0);
    g = __builtin_amdgcn_mfma_f32_16x16x32_bf16(a1, b1, g, 0, 0, 0);
  }
#pragma unroll
  for (int r = 0; r < 4; ++r) {
    const float gv = (l15 <= 4 * hi + r) ? g[r] : 0.f;
    Gs[wv][4 * hi + r][l15] = f2bf(gv);
  }
  const char* gsb = (const char*)&Gs[wv][0][0];
  const char* vtb = (const char*)&VT[wv][0][0];
  bf16x8 aG = *(const bf16x8*)(gsb + l15 * 64 + 16 * hi);
#pragma unroll
  for (int nt = 0; nt < 4; ++nt) {
    bf16x8 bV = *(const bf16x8*)(vtb + (nt * 16 + l15) * 64 + 16 * hi);
    f32x4 y = __builtin_amdgcn_mfma_f32_16x16x32_bf16(aG, bV, z, 0, 0, 0);
#pragma unroll
    for (int r = 0; r < 4; ++r)
      yi[(size_t)cid * 1024 + (4 * hi + r) * 64 + nt * 16 + l15] = y[r];
  }
  const char* keb = (const char*)&KdET[wv][0][0];
#pragma unroll
  for (int mt = 0; mt < 4; ++mt) {
    bf16x8 aT = *(const bf16x8*)(keb + (mt * 16 + l15) * 64 + 16 * hi);
#pragma unroll
    for (int nt = 0; nt < 4; ++nt) {
      bf16x8 bV = *(const bf16x8*)(vtb + (nt * 16 + l15) * 64 + 16 * hi);
      f32x4 t4 = __builtin_amdgcn_mfma_f32_16x16x32_bf16(aT, bV, z, 0, 0, 0);
#pragma unroll
      for (int r = 0; r < 4; ++r)
        TCG[(size_t)cid * 4096 + (mt * 16 + 4 * hi + r) * 64 + nt * 16 + l15] = f2bf(t4[r]);
    }
  }
}

// ------------------------------- scanB --------------------------------------
__global__ __launch_bounds__(256) void scanB_kernel(
    unsigned short* __restrict__ TCG, const float* __restrict__ Dg) {
  const int bh = blockIdx.x;
  const int tid = threadIdx.x, wv = tid >> 6, lane = tid & 63;
  const int bkb = wv * 8;
  float Cr[8], Ci[8];
#pragma unroll
  for (int i = 0; i < 8; ++i) { Cr[i] = 0.f; Ci[i] = 0.f; }
  for (int c0 = 0; c0 < 128; c0 += 2) {
    float tr[2][8], ti[2][8]; float2 dv[2][8];
#pragma unroll
    for (int u = 0; u < 2; ++u) {
      const size_t cid = (size_t)bh * 128 + c0 + u;
#pragma unroll
      for (int i = 0; i < 8; ++i) {
        tr[u][i] = bf2f(TCG[cid * 4096 + (bkb + i) * 64 + lane]);
        ti[u][i] = bf2f(TCG[cid * 4096 + (32 + bkb + i) * 64 + lane]);
        dv[u][i] = *(const float2*)&Dg[(cid * 32 + bkb + i) * 2];
      }
    }
    __syncthreads();
#pragma unroll
    for (int u = 0; u < 2; ++u) {
      const size_t cid = (size_t)bh * 128 + c0 + u;
#pragma unroll
      for (int i = 0; i < 8; ++i) {
        ((unsigned int*)TCG)[cid * 2048 + (size_t)lane * 32 + bkb + i] = pack2(Cr[i], -Ci[i]);
        const float nr = fmaf(dv[u][i].x, Cr[i], fmaf(-dv[u][i].y, Ci[i], tr[u][i]));
        const float ni = fmaf(dv[u][i].x, Ci[i], fmaf(dv[u][i].y, Cr[i], ti[u][i]));
        Cr[i] = nr; Ci[i] = ni;
      }
    }
  }
}

// ------------------------------- attn_cross ---------------------------------
__global__ __launch_bounds__(256) void attn_cross(
    const float* __restrict__ yi, const unsigned short* __restrict__ QG,
    const unsigned short* __restrict__ TCG, unsigned short* __restrict__ attn) {
  const int c = blockIdx.x, bh = blockIdx.y;
  const int b = bh >> 4, h = bh & 15;
  const int tid = threadIdx.x, wv = tid >> 6, lane = tid & 63;
  const int sc = c * 4 + wv, cid = bh * 128 + sc;
  const int mw = b * 2048 + sc * 16;
  __shared__ unsigned short Cp[4][64][64];
  __shared__ unsigned short Qs[4][16][64];
  unsigned int* cp32 = (unsigned int*)&Cp[wv][0][0];
  const unsigned int* cg = (const unsigned int*)TCG + (size_t)cid * 2048;
  for (int ii = 0; ii < 32; ++ii) {
    const int flat = ii * 64 + lane;
    const int row = flat >> 5, col = flat & 31;
    cp32[(row * 32 + col) ^ ((row & 7) << 2)] = cg[flat];
  }
  unsigned int* qs32 = (unsigned int*)&Qs[wv][0][0];
  const unsigned int* qg = (const unsigned int*)QG + (size_t)cid * 512;
  for (int ii = 0; ii < 8; ++ii) {
    const int flat = ii * 64 + lane;
    const int row = flat >> 5, col = flat & 31;
    qs32[(row * 32 + col) ^ ((row & 7) << 2)] = qg[flat];
  }
  const int l15 = lane & 15, hi = lane >> 4;
  const char* qb = (const char*)&Qs[wv][0][0];
  const char* cb = (const char*)&Cp[wv][0][0];
  bf16x8 a0 = *(const bf16x8*)(qb + l15 * 128 + ((16 * hi) ^ ((l15 & 7) << 4)));
  bf16x8 a1 = *(const bf16x8*)(qb + l15 * 128 + ((64 + 16 * hi) ^ ((l15 & 7) << 4)));
  f32x4 z = {};
#pragma unroll
  for (int nt = 0; nt < 4; ++nt) {
    const int vr = nt * 16 + l15;
    bf16x8 b0 = *(const bf16x8*)(cb + vr * 128 + ((16 * hi) ^ ((vr & 7) << 4)));
    bf16x8 b1 = *(const bf16x8*)(cb + vr * 128 + ((64 + 16 * hi) ^ ((vr & 7) << 4)));
    f32x4 y = __builtin_amdgcn_mfma_f32_16x16x32_bf16(a0, b0, z, 0, 0, 0);
    y = __builtin_amdgcn_mfma_f32_16x16x32_bf16(a1, b1, y, 0, 0, 0);
#pragma unroll
    for (int r = 0; r < 4; ++r) {
      const int t = 4 * hi + r;
      const float out = y[r] + yi[(size_t)cid * 1024 + t * 64 + vr];
      attn[(size_t)(mw + t) * 1024 + h * 64 + vr] = f2bf(out);
    }
  }
}

// ---------------------------------------------------------------------------
extern "C" void kernel_launch(void* const* d_in, const int* in_sizes, int n_in,
                              void* d_out, int out_size, void* d_ws, size_t ws_size,
                              hipStream_t stream) {
  const float* x   = (const float*)d_in[0];
  const float* Wq  = (const float*)d_in[1];
  const float* bq  = (const float*)d_in[2];
  const float* Wk  = (const float*)d_in[3];
  const float* bk_ = (const float*)d_in[4];
  const float* Wv  = (const float*)d_in[5];
  const float* bv  = (const float*)d_in[6];
  const float* Wo  = (const float*)d_in[7];
  const float* bo  = (const float*)d_in[8];
  const float* n1g = (const float*)d_in[9];
  const float* n1b = (const float*)d_in[10];
  const float* n2g = (const float*)d_in[11];
  const float* n2b = (const float*)d_in[12];
  const float* thb = (const float*)d_in[13];
  const float* tw1 = (const float*)d_in[14];
  const float* tw2 = (const float*)d_in[15];
  const float* lamb= (const float*)d_in[16];
  const float* eta = (const float*)d_in[17];
  const float* Wf1 = (const float*)d_in[18];
  const float* bf1 = (const float*)d_in[19];
  const float* Wf2 = (const float*)d_in[20];
  const float* bf2 = (const float*)d_in[21];

  char* ws = (char*)d_ws;
  size_t off = 0;
  auto alloc = [&](size_t bytes) {
    size_t r = off;
    off += (bytes + 255) & ~(size_t)255;
    return r;
  };
  unsigned short* WCAT = (unsigned short*)(ws + alloc(3200ull * 1024 * 2));
  unsigned short* WOT  = (unsigned short*)(ws + alloc(1024ull * 1024 * 2));
  unsigned short* WF1T = (unsigned short*)(ws + alloc(4096ull * 1024 * 2));
  unsigned short* WF2T = (unsigned short*)(ws + alloc(1024ull * 4096 * 2));
  float* BIASC = (float*)(ws + alloc(3200ull * 4));
  unsigned short* XN = (unsigned short*)(ws + alloc(8192ull * 1024 * 2));  // also LN2 out
  char* QKVbase = ws + alloc(8192ull * 4096 * 2);   // QKV bf16 / GBUF
  unsigned short* QKV = (unsigned short*)QKVbase;
  unsigned short* GBUF = (unsigned short*)QKVbase;
  float* THETA = (float*)(ws + alloc(8192ull * 512 * 4));   // also ATTN bf16
  unsigned short* ATTN = (unsigned short*)THETA;
  float* YI = (float*)(ws + alloc(8192ull * 1024 * 4));     // also X1
  float* X1 = YI;
  unsigned short* QG = (unsigned short*)(ws + alloc(8192ull * 1024 * 2));
  unsigned short* TCG = (unsigned short*)(ws + alloc(8192ull * 4096 * 2)); // T then Cpack
  float* DG = (float*)(ws + alloc(8192ull * 32 * 2 * 4));

  if (ws_size < off) {
    fill_kernel<<<dim3((out_size + 255) / 256), dim3(256), 0, stream>>>((float*)d_out, 12345.0f, out_size);
    return;
  }

  const dim3 b256(256), b32x8(32, 8);

  // weight prep
  prep_wcat<<<dim3(100, 32), b32x8, 0, stream>>>(Wq, Wk, Wv, tw1, WCAT);
  transpose_bf16<<<dim3(32, 32), b32x8, 0, stream>>>(Wo, WOT, 1024, 1024);
  transpose_bf16<<<dim3(128, 32), b32x8, 0, stream>>>(Wf1, WF1T, 1024, 4096);
  transpose_bf16<<<dim3(32, 128), b32x8, 0, stream>>>(Wf2, WF2T, 4096, 1024);
  biascat_kernel<<<dim3(13), b256, 0, stream>>>(bq, bk_, bv, BIASC);

  // LN1 -> xn (bf16)
  ln_kernel<<<dim3(8192), b256, 0, stream>>>(x, n1g, n1b, XN);
  // QKV + lora1 (bf16 out)
  gemm_kernel<3><<<dim3(25, 64), b256, 0, stream>>>(XN, WCAT, BIASC, nullptr, QKV, 3200, 1024);
  // lora2 -> theta
  lora2_kernel<<<dim3(256), b256, 0, stream>>>(QKV, tw2, thb, THETA);
  // attention
  attn_intra<<<dim3(32, 64), b256, 0, stream>>>(QKV, THETA, lamb, eta, YI, QG, TCG, DG);
  scanB_kernel<<<dim3(64), b256, 0, stream>>>(TCG, DG);
  attn_cross<<<dim3(32, 64), b256, 0, stream>>>(YI, QG, TCG, ATTN);
  // x1 = x + attn@Wo + bo
  gemm_kernel<1><<<dim3(8, 64), b256, 0, stream>>>(ATTN, WOT, bo, x, X1, 1024, 1024);
  // LN2
  ln_kernel<<<dim3(8192), b256, 0, stream>>>(X1, n2g, n2b, XN);
  // FFN1 (gelu, bf16 out)
  gemm_kernel<2><<<dim3(32, 64), b256, 0, stream>>>(XN, WF1T, bf1, nullptr, GBUF, 4096, 1024);
  // FFN2 (+X1 residual, fp32 out)
  gemm_kernel<1><<<dim3(8, 64), b256, 0, stream>>>(GBUF, WF2T, bf2, X1, d_out, 1024, 4096);
}